// Round 9
// baseline (72.879 us; speedup 1.0000x reference)
//
#include <hip/hip_runtime.h>

#define N_ 256
#define C_ 3
#define T_ 600
#define V_ 25
#define M_ 2
#define NSLAB (N_ * C_)        // 768
#define TY 20
#define CH (T_ / TY)           // 30 t-rows per ty-chunk

// Fused single-pass kernel. One block per (n,c) slab, blockDim (25,20).
// Streaming phase = round-6 structure (supply-bound optimum): tx = joint v,
// ty owns a 30-row t-chunk, float2 loads, rolling-register temporal diff,
// seam diff t1-1 -> t1 (exact 599-diff partition: 19*(29+1) + 29).
//
// Cross-block handoff (G16-safe): ALL cross-block data moves via device-scope
// atomic RMWs (coherent-point ops, m20): publish with atomicAdd into zeroed
// absP/sqP; read back with atomicAdd(ptr, 0.0f). Ordering: publishing lanes
// (tx=0..24, ty=0) are lanes 0..24 of wave 0; the ACQ_REL counter bump by
// lane 0 drains the WAVE's vmcnt -> all 25 lanes' RMWs complete first.
//
// ROUND-8 BUG WAS ARITHMETIC, NOT SYNC: divisor is 23,040,000 (=256*3*600*25*2),
// not 230,400,000. Deterministic 10x-small output in rounds 7-8.
__global__ __launch_bounds__(512) void fused_kernel(
    const float* __restrict__ x, const float* __restrict__ y,
    float* __restrict__ absP, float* __restrict__ sqP,
    float* __restrict__ accOut, int* __restrict__ cntN, int* __restrict__ cntAll,
    float* __restrict__ out)
{
    const int slab = blockIdx.x;          // n*3 + c
    const int tx   = threadIdx.x;         // 0..24 == joint v
    const int ty   = threadIdx.y;         // 0..19
    const int n    = slab / C_;

    const float2* __restrict__ xs = reinterpret_cast<const float2*>(x) + (size_t)slab * (T_ * V_);
    const float2* __restrict__ ys = reinterpret_cast<const float2*>(y) + (size_t)slab * (T_ * V_);

    const int t0 = ty * CH;
    const int t1 = t0 + CH;

    float2 xc = xs[t0 * V_ + tx];
    float2 yc = ys[t0 * V_ + tx];
    float ex = xc.x - yc.x, ey = xc.y - yc.y;
    float sq = ex * ex + ey * ey;
    float mv = 0.0f;

    for (int t = t0 + 1; t < t1; ++t) {
        float2 xn = xs[t * V_ + tx];
        float2 yn = ys[t * V_ + tx];
        mv += fabsf(xn.x - xc.x) + fabsf(xn.y - xc.y);
        ex = xn.x - yn.x; ey = xn.y - yn.y;
        sq += ex * ex + ey * ey;
        xc = xn;
    }
    if (t1 < T_) {                         // seam diff (t1-1 -> t1)
        float2 xn = xs[t1 * V_ + tx];
        mv += fabsf(xn.x - xc.x) + fabsf(xn.y - xc.y);
    }

    __shared__ float redA[TY][V_ + 1];
    __shared__ float redS[TY][V_ + 1];
    __shared__ int lastFlag;
    redA[ty][tx] = mv;
    redS[ty][tx] = sq;
    __syncthreads();

    float a = 0.0f, s = 0.0f;
    if (ty == 0) {
        #pragma unroll
        for (int j = 0; j < TY; ++j) { a += redA[j][tx]; s += redS[j][tx]; }
        // publish via device-scope RMW (coherent point); buffers pre-zeroed
        atomicAdd(&absP[slab * V_ + tx], a);
        atomicAdd(&sqP [slab * V_ + tx], s);
        if (tx == 0) {
            int old = __hip_atomic_fetch_add(&cntN[n], 1, __ATOMIC_ACQ_REL, __HIP_MEMORY_SCOPE_AGENT);
            lastFlag = (old == C_ - 1) ? 1 : 0;
        }
    }
    __syncthreads();                       // lastFlag block-uniform below

    if (lastFlag) {
        __shared__ float sA[V_], sW[V_];
        if (ty == 0) {
            const int myc = slab - n * C_;
            float aN = a, sN = s;          // own slab from registers
            #pragma unroll
            for (int c = 0; c < C_; ++c) {
                if (c == myc) continue;
                const int idx = (n * C_ + c) * V_ + tx;
                aN += atomicAdd(&absP[idx], 0.0f);   // RMW-read: coherent, never stale
                sN += atomicAdd(&sqP [idx], 0.0f);
            }
            sA[tx] = aN;
            sW[tx] = aN * sN;
        }
        __syncthreads();
        if (ty == 0 && tx == 0) {
            float sumA = 0.0f, sumW = 0.0f;
            #pragma unroll
            for (int v = 0; v < V_; ++v) { sumA += sA[v]; sumW += sW[v]; }
            const float contrib = (float)V_ * sumW / sumA;
            atomicAdd(accOut, contrib);
            const int done = __hip_atomic_fetch_add(cntAll, 1, __ATOMIC_ACQ_REL, __HIP_MEMORY_SCOPE_AGENT);
            if (done == N_ - 1) {
                const float tot = atomicAdd(accOut, 0.0f);   // RMW-read of full sum
                out[0] = tot / 23040000.0f;   // 256*3*600*25*2 = 23,040,000
            }
        }
    }
}

extern "C" void kernel_launch(void* const* d_in, const int* in_sizes, int n_in,
                              void* d_out, int out_size, void* d_ws, size_t ws_size,
                              hipStream_t stream) {
    const float* x = (const float*)d_in[0];
    const float* y = (const float*)d_in[1];
    float* out    = (float*)d_out;

    float* absP   = (float*)d_ws;                 // NSLAB*V_ floats (RMW-accumulated)
    float* sqP    = absP + NSLAB * V_;            // NSLAB*V_ floats
    float* accOut = sqP + NSLAB * V_;             // 1 float
    int*   cntN   = (int*)(accOut + 1);           // N_ ints
    int*   cntAll = cntN + N_;                    // 1 int

    // zero everything we RMW into: 2*19200 floats + 1 float + 257 ints ~ 154 KB
    const size_t zbytes = (size_t)(2 * NSLAB * V_ + 1 + N_ + 1) * 4;
    hipMemsetAsync(d_ws, 0, zbytes, stream);

    dim3 blk(V_, TY);                             // (25,20) = 500 threads
    fused_kernel<<<NSLAB, blk, 0, stream>>>(x, y, absP, sqP, accOut, cntN, cntAll, out);
}